// Round 1
// baseline (441.662 us; speedup 1.0000x reference)
//
#include <hip/hip_runtime.h>
#include <hip/hip_bf16.h>
#include <stdint.h>

typedef unsigned short u16;
typedef __attribute__((ext_vector_type(8))) short bf16x8;
typedef __attribute__((ext_vector_type(4))) float f32x4;
typedef __attribute__((ext_vector_type(4))) unsigned short u16x4;

#define DEVI static __device__ __forceinline__

DEVI u16 f2bf(float f) {
    unsigned int u = __builtin_bit_cast(unsigned int, f);
    return (u16)((u + 0x7fffu + ((u >> 16) & 1u)) >> 16);
}

DEVI void async_copy16(const void* g, void* l) {
    __builtin_amdgcn_global_load_lds((const __attribute__((address_space(1))) void*)g,
                                     (__attribute__((address_space(3))) void*)l,
                                     16, 0, 0);
}

// ---------------- weight transpose + f32->bf16 convert: src[K][N] -> dst[N][K] ----------------
__global__ __launch_bounds__(256) void tcvt_kernel(const float* __restrict__ src,
                                                   u16* __restrict__ dst,
                                                   int K, int N) {
    __shared__ float tile[32][33];
    const int k0 = blockIdx.x * 32, n0 = blockIdx.y * 32;
    const int t = threadIdx.x;
    const int c = t & 31, r0 = t >> 5;   // 8 rows per pass
#pragma unroll
    for (int p = 0; p < 4; ++p) {
        const int r = r0 + p * 8;
        tile[r][c] = src[(size_t)(k0 + r) * N + n0 + c];
    }
    __syncthreads();
#pragma unroll
    for (int p = 0; p < 4; ++p) {
        const int r = r0 + p * 8;
        dst[(size_t)(n0 + r) * K + k0 + c] = f2bf(tile[c][r]);
    }
}

// ---------------- LayerNorm (f32 in) -> bf16 out, one block per row of 1024 ----------------
__global__ __launch_bounds__(256) void ln_kernel(const float* __restrict__ x,
                                                 const float* __restrict__ gw,
                                                 const float* __restrict__ bw,
                                                 u16* __restrict__ out) {
    const int row = blockIdx.x;
    const int t = threadIdx.x;
    const float4 v = ((const float4*)(x + (size_t)row * 1024))[t];
    float s  = v.x + v.y + v.z + v.w;
    float ss = v.x * v.x + v.y * v.y + v.z * v.z + v.w * v.w;
#pragma unroll
    for (int off = 32; off > 0; off >>= 1) {
        s  += __shfl_down(s, off);
        ss += __shfl_down(ss, off);
    }
    __shared__ float red[8];
    const int wv = t >> 6;
    if ((t & 63) == 0) { red[wv] = s; red[4 + wv] = ss; }
    __syncthreads();
    if (t == 0) {
        red[0] = red[0] + red[1] + red[2] + red[3];
        red[4] = red[4] + red[5] + red[6] + red[7];
    }
    __syncthreads();
    const float mean = red[0] * (1.0f / 1024.0f);
    const float var  = red[4] * (1.0f / 1024.0f) - mean * mean;
    const float rstd = rsqrtf(var + 1e-5f);
    const float4 gv = ((const float4*)gw)[t];
    const float4 bv = ((const float4*)bw)[t];
    u16x4 o;
    o[0] = f2bf((v.x - mean) * rstd * gv.x + bv.x);
    o[1] = f2bf((v.y - mean) * rstd * gv.y + bv.y);
    o[2] = f2bf((v.z - mean) * rstd * gv.z + bv.z);
    o[3] = f2bf((v.w - mean) * rstd * gv.w + bv.w);
    ((u16x4*)out)[(size_t)row * 256 + t] = o;
}

// ---------------- GEMM: A[M,K] bf16 x Bt[N,K] bf16 -> epilogue ----------------
// EPI 0: QKV split (out0=q [B,H,L,64] scaled 0.125, out1=k [B,H,L,64], out2=vt [B,H,64,L])
// EPI 1: out0 = f32, val + bias + res   (proj + residual)
// EPI 2: out0 = bf16 gelu(val + bias)   (fc1)
// EPI 3: out0 = f32, val + bias + res   (fc2 + residual -> d_out)
template <int BM, int BN, int EPI>
__global__ __launch_bounds__(256, 2) void gemm_bf16(const u16* __restrict__ A,
                                                    const u16* __restrict__ Bt,
                                                    const float* __restrict__ bias,
                                                    const float* __restrict__ res,
                                                    void* __restrict__ out0,
                                                    void* __restrict__ out1,
                                                    void* __restrict__ out2,
                                                    int M, int N, int K) {
    constexpr int WM = BM / 2, WN = BN / 2;
    constexpr int FM = WM / 16, FN = WN / 16;
    __shared__ __align__(16) short Asm[BM * 32];
    __shared__ __align__(16) short Bsm[BN * 32];
    const int tid = threadIdx.x;
    const int lane = tid & 63, wv = tid >> 6;
    const int wr = wv >> 1, wc = wv & 1;
    const int g = lane >> 4, qq = lane & 15;
    const int n0 = blockIdx.x * BN, m0 = blockIdx.y * BM;

    f32x4 acc[FM][FN] = {};

    const char* srcA = (const char*)A + ((size_t)m0 * K) * 2;
    const char* srcB = (const char*)Bt + ((size_t)n0 * K) * 2;
    const size_t strideAB = (size_t)K * 2;

    for (int k0 = 0; k0 < K; k0 += 32) {
        // stage A tile [BM][32] and B tile [BN][32] (both row-major, contiguous)
#pragma unroll
        for (int i = 0; i < BM * 64 / 4096; ++i) {
            const int b = i * 4096 + wv * 1024 + lane * 16;
            const int row = b >> 6, colb = b & 63;
            async_copy16(srcA + (size_t)row * strideAB + (size_t)k0 * 2 + colb,
                         (char*)Asm + i * 4096 + wv * 1024);
        }
#pragma unroll
        for (int i = 0; i < BN * 64 / 4096; ++i) {
            const int b = i * 4096 + wv * 1024 + lane * 16;
            const int row = b >> 6, colb = b & 63;
            async_copy16(srcB + (size_t)row * strideAB + (size_t)k0 * 2 + colb,
                         (char*)Bsm + i * 4096 + wv * 1024);
        }
        __syncthreads();

        bf16x8 af[FM], bfr[FN];
#pragma unroll
        for (int fm = 0; fm < FM; ++fm) {
            const int row = wr * WM + fm * 16 + qq;
            af[fm] = *(const bf16x8*)(&Asm[row * 32 + g * 8]);
        }
#pragma unroll
        for (int fn = 0; fn < FN; ++fn) {
            const int row = wc * WN + fn * 16 + qq;
            bfr[fn] = *(const bf16x8*)(&Bsm[row * 32 + g * 8]);
        }
#pragma unroll
        for (int fm = 0; fm < FM; ++fm) {
#pragma unroll
            for (int fn = 0; fn < FN; ++fn) {
                acc[fm][fn] = __builtin_amdgcn_mfma_f32_16x16x32_bf16(af[fm], bfr[fn],
                                                                      acc[fm][fn], 0, 0, 0);
            }
        }
        __syncthreads();
    }

    // epilogue: lane holds D[(g*4 + r)][qq] per 16x16 fragment
    const int g4 = g * 4;
#pragma unroll
    for (int fm = 0; fm < FM; ++fm) {
#pragma unroll
        for (int fn = 0; fn < FN; ++fn) {
            const int mrow = m0 + wr * WM + fm * 16 + g4;
            const int ncol = n0 + wc * WN + fn * 16 + qq;
            const float bs = bias[ncol];
            if constexpr (EPI == 0) {
                const int sec = ncol >> 10;
                const int hd_ = ncol & 1023;
                const int hh = hd_ >> 6, dd = hd_ & 63;
                if (sec == 2) {
                    const int b_ = mrow >> 11, l_ = mrow & 2047;
                    u16x4 pk;
#pragma unroll
                    for (int r = 0; r < 4; ++r) pk[r] = f2bf(acc[fm][fn][r] + bs);
                    *(u16x4*)((u16*)out2 + ((size_t)((b_ * 16 + hh) * 64 + dd)) * 2048 + l_) = pk;
                } else {
                    u16* dst = (sec == 0) ? (u16*)out0 : (u16*)out1;
                    const float sc = (sec == 0) ? 0.125f : 1.0f;
#pragma unroll
                    for (int r = 0; r < 4; ++r) {
                        const int mr = mrow + r;
                        const int b_ = mr >> 11, l_ = mr & 2047;
                        dst[((size_t)((b_ * 16 + hh) * 2048 + l_)) * 64 + dd] =
                            f2bf((acc[fm][fn][r] + bs) * sc);
                    }
                }
            } else if constexpr (EPI == 1 || EPI == 3) {
                float* dst = (float*)out0;
#pragma unroll
                for (int r = 0; r < 4; ++r) {
                    const int mr = mrow + r;
                    dst[(size_t)mr * N + ncol] = acc[fm][fn][r] + bs + res[(size_t)mr * N + ncol];
                }
            } else {
                u16* dst = (u16*)out0;
#pragma unroll
                for (int r = 0; r < 4; ++r) {
                    float v = acc[fm][fn][r] + bs;
                    v = 0.5f * v * (1.0f + erff(v * 0.70710678118f));
                    dst[(size_t)(mrow + r) * N + ncol] = f2bf(v);
                }
            }
        }
    }
}

// ---------------- causal flash attention ----------------
// Q [BH][2048][64] (pre-scaled), K [BH][2048][64], Vt [BH][64][2048] -> Y bf16 [4096][1024]
// One wave owns 16 q rows; swapped QK^T (S^T = K*Q^T) so softmax state is lane-local.
__global__ __launch_bounds__(256, 2) void attn_kernel(const u16* __restrict__ Q,
                                                      const u16* __restrict__ Kk,
                                                      const u16* __restrict__ Vt,
                                                      u16* __restrict__ Y) {
    const int bh = blockIdx.y;
    const int b_ = bh >> 4, hh = bh & 15;
    const int tid = threadIdx.x;
    const int wv = tid >> 6, lane = tid & 63;
    const int g = lane >> 4, qi = lane & 15;
    const int q0 = blockIdx.x * 64 + wv * 16;
    const int qg = q0 + qi;
    __shared__ __align__(16) u16 Pl[4][16][72];   // per-wave P[q][key], padded stride 72

    const u16* Qb = Q + ((size_t)bh * 2048 + q0) * 64;
    const u16* Kb = Kk + (size_t)bh * 2048 * 64;
    const u16* Vb = Vt + (size_t)bh * 64 * 2048;

    bf16x8 qf[2];
#pragma unroll
    for (int ks = 0; ks < 2; ++ks)
        qf[ks] = *(const bf16x8*)(Qb + qi * 64 + ks * 32 + g * 8);

    f32x4 oacc[4] = {};
    float m_run = -1e30f, l_run = 0.0f;
    const int ntile = ((q0 + 15) >> 6) + 1;

    for (int kt = 0; kt < ntile; ++kt) {
        const int key0 = kt * 64;
        f32x4 sacc[4] = {};
#pragma unroll
        for (int ks = 0; ks < 2; ++ks) {
#pragma unroll
            for (int kc = 0; kc < 4; ++kc) {
                const bf16x8 ak =
                    *(const bf16x8*)(Kb + (size_t)(key0 + kc * 16 + qi) * 64 + ks * 32 + g * 8);
                sacc[kc] = __builtin_amdgcn_mfma_f32_16x16x32_bf16(ak, qf[ks], sacc[kc], 0, 0, 0);
            }
        }
        // lane holds S[q=qi][key = key0 + kc*16 + g*4 + r]
        float p[4][4];
        float mymax = -1e30f;
#pragma unroll
        for (int kc = 0; kc < 4; ++kc) {
#pragma unroll
            for (int r = 0; r < 4; ++r) {
                const int key = key0 + kc * 16 + g * 4 + r;
                float sv = sacc[kc][r];
                if (key > qg) sv = -__builtin_inff();
                p[kc][r] = sv;
                mymax = fmaxf(mymax, sv);
            }
        }
        mymax = fmaxf(mymax, __shfl_xor(mymax, 16));
        mymax = fmaxf(mymax, __shfl_xor(mymax, 32));
        const float m_new = fmaxf(m_run, mymax);
        const float alpha = __expf(m_run - m_new);
        float lsum = 0.0f;
#pragma unroll
        for (int kc = 0; kc < 4; ++kc) {
#pragma unroll
            for (int r = 0; r < 4; ++r) {
                const float e = __expf(p[kc][r] - m_new);
                p[kc][r] = e;
                lsum += e;
            }
        }
        lsum += __shfl_xor(lsum, 16);
        lsum += __shfl_xor(lsum, 32);
        l_run = l_run * alpha + lsum;
        m_run = m_new;
#pragma unroll
        for (int c = 0; c < 4; ++c) {
#pragma unroll
            for (int r = 0; r < 4; ++r) oacc[c][r] *= alpha;
        }
        // P -> LDS [q][key] (bf16), then reload as PV B-operand fragments
#pragma unroll
        for (int kc = 0; kc < 4; ++kc) {
            u16x4 pk;
#pragma unroll
            for (int r = 0; r < 4; ++r) pk[r] = f2bf(p[kc][r]);
            *(u16x4*)(&Pl[wv][qi][kc * 16 + g * 4]) = pk;
        }
        bf16x8 pb[2];
#pragma unroll
        for (int ks = 0; ks < 2; ++ks)
            pb[ks] = *(const bf16x8*)(&Pl[wv][qi][ks * 32 + g * 8]);
        // O^T += V^T * P^T : A = Vt rows (d), B = P
#pragma unroll
        for (int ks = 0; ks < 2; ++ks) {
#pragma unroll
            for (int c = 0; c < 4; ++c) {
                const bf16x8 av =
                    *(const bf16x8*)(Vb + (size_t)(c * 16 + qi) * 2048 + key0 + ks * 32 + g * 8);
                oacc[c] = __builtin_amdgcn_mfma_f32_16x16x32_bf16(av, pb[ks], oacc[c], 0, 0, 0);
            }
        }
    }

    const float inv = 1.0f / l_run;
#pragma unroll
    for (int c = 0; c < 4; ++c) {
        u16x4 o;
#pragma unroll
        for (int r = 0; r < 4; ++r) o[r] = f2bf(oacc[c][r] * inv);
        *(u16x4*)(&Y[((size_t)(b_ * 2048 + qg)) * 1024 + hh * 64 + c * 16 + g * 4]) = o;
    }
}

// ---------------- host ----------------
extern "C" void kernel_launch(void* const* d_in, const int* in_sizes, int n_in,
                              void* d_out, int out_size, void* d_ws, size_t ws_size,
                              hipStream_t stream) {
    (void)in_sizes; (void)n_in; (void)out_size;
    const float* x      = (const float*)d_in[0];
    const float* w_qkv  = (const float*)d_in[2];
    const float* b_qkv  = (const float*)d_in[3];
    const float* w_proj = (const float*)d_in[4];
    const float* b_proj = (const float*)d_in[5];
    const float* w_fc1  = (const float*)d_in[6];
    const float* b_fc1  = (const float*)d_in[7];
    const float* w_fc2  = (const float*)d_in[8];
    const float* b_fc2  = (const float*)d_in[9];
    const float* g1     = (const float*)d_in[10];
    const float* be1    = (const float*)d_in[11];
    const float* g2     = (const float*)d_in[12];
    const float* be2    = (const float*)d_in[13];

    char* ws = (char*)d_ws;
    size_t off = 0;
    auto alloc = [&](size_t bytes) { size_t r = off; off += (bytes + 255) & ~(size_t)255; return r; };
    u16*   wt_qkv = (u16*)(ws + alloc((size_t)3072 * 1024 * 2));
    u16*   wt_prj = (u16*)(ws + alloc((size_t)1024 * 1024 * 2));
    u16*   wt_fc1 = (u16*)(ws + alloc((size_t)4096 * 1024 * 2));
    u16*   wt_fc2 = (u16*)(ws + alloc((size_t)1024 * 4096 * 2));
    u16*   hbuf   = (u16*)(ws + alloc((size_t)4096 * 1024 * 2));   // ln out (reused for ln2)
    float* x1     = (float*)(ws + alloc((size_t)4096 * 1024 * 4)); // residual after attn
    char*  big    = ws + alloc((size_t)33554432);                  // q,k,vt,y  OR  act
    u16* qb  = (u16*)(big);
    u16* kb  = (u16*)(big + 8388608);
    u16* vtb = (u16*)(big + 16777216);
    u16* yb  = (u16*)(big + 25165824);
    u16* act = (u16*)(big);                                        // reuse after attention is done
    if (off > ws_size) return;  // workspace too small: bail (harness will flag mismatch)

    const dim3 blk(256);
    // weights -> bf16 transposed [N][K]
    tcvt_kernel<<<dim3(32, 96), blk, 0, stream>>>(w_qkv, wt_qkv, 1024, 3072);
    tcvt_kernel<<<dim3(32, 32), blk, 0, stream>>>(w_proj, wt_prj, 1024, 1024);
    tcvt_kernel<<<dim3(32, 128), blk, 0, stream>>>(w_fc1, wt_fc1, 1024, 4096);
    tcvt_kernel<<<dim3(128, 32), blk, 0, stream>>>(w_fc2, wt_fc2, 4096, 1024);

    // LN1
    ln_kernel<<<dim3(4096), blk, 0, stream>>>(x, g1, be1, hbuf);
    // QKV gemm + head-split epilogue
    gemm_bf16<128, 128, 0><<<dim3(24, 32), blk, 0, stream>>>(hbuf, wt_qkv, b_qkv, nullptr,
                                                             qb, kb, vtb, 4096, 3072, 1024);
    // attention
    attn_kernel<<<dim3(32, 32), blk, 0, stream>>>(qb, kb, vtb, yb);
    // proj + residual (f32)
    gemm_bf16<64, 128, 1><<<dim3(8, 64), blk, 0, stream>>>(yb, wt_prj, b_proj, x,
                                                           x1, nullptr, nullptr, 4096, 1024, 1024);
    // LN2
    ln_kernel<<<dim3(4096), blk, 0, stream>>>(x1, g2, be2, hbuf);
    // FC1 + GELU
    gemm_bf16<128, 128, 2><<<dim3(32, 32), blk, 0, stream>>>(hbuf, wt_fc1, b_fc1, nullptr,
                                                             act, nullptr, nullptr, 4096, 4096, 1024);
    // FC2 + residual -> out (f32)
    gemm_bf16<64, 128, 3><<<dim3(8, 64), blk, 0, stream>>>(act, wt_fc2, b_fc2, x1,
                                                           (float*)d_out, nullptr, nullptr,
                                                           4096, 1024, 4096);
}

// Round 2
// 293.063 us; speedup vs baseline: 1.5071x; 1.5071x over previous
//
#include <hip/hip_runtime.h>
#include <hip/hip_bf16.h>
#include <stdint.h>

typedef unsigned short u16;
typedef __attribute__((ext_vector_type(8))) short bf16x8;
typedef __attribute__((ext_vector_type(4))) float f32x4;
typedef __attribute__((ext_vector_type(4))) unsigned short u16x4;

#define DEVI static __device__ __forceinline__

DEVI u16 f2bf(float f) {
    unsigned int u = __builtin_bit_cast(unsigned int, f);
    return (u16)((u + 0x7fffu + ((u >> 16) & 1u)) >> 16);
}

DEVI void async_copy16(const void* g, void* l) {
    __builtin_amdgcn_global_load_lds((const __attribute__((address_space(1))) void*)g,
                                     (__attribute__((address_space(3))) void*)l,
                                     16, 0, 0);
}

// ---------------- weight transpose + f32->bf16 convert: src[K][N] -> dst[N][K] ----------------
__global__ __launch_bounds__(256) void tcvt_kernel(const float* __restrict__ src,
                                                   u16* __restrict__ dst,
                                                   int K, int N) {
    __shared__ float tile[32][33];
    const int k0 = blockIdx.x * 32, n0 = blockIdx.y * 32;
    const int t = threadIdx.x;
    const int c = t & 31, r0 = t >> 5;   // 8 rows per pass
#pragma unroll
    for (int p = 0; p < 4; ++p) {
        const int r = r0 + p * 8;
        tile[r][c] = src[(size_t)(k0 + r) * N + n0 + c];
    }
    __syncthreads();
#pragma unroll
    for (int p = 0; p < 4; ++p) {
        const int r = r0 + p * 8;
        dst[(size_t)(n0 + r) * K + k0 + c] = f2bf(tile[c][r]);
    }
}

// ---------------- LayerNorm (f32 in) -> bf16 out, one block per row of 1024 ----------------
__global__ __launch_bounds__(256) void ln_kernel(const float* __restrict__ x,
                                                 const float* __restrict__ gw,
                                                 const float* __restrict__ bw,
                                                 u16* __restrict__ out) {
    const int row = blockIdx.x;
    const int t = threadIdx.x;
    const float4 v = ((const float4*)(x + (size_t)row * 1024))[t];
    float s  = v.x + v.y + v.z + v.w;
    float ss = v.x * v.x + v.y * v.y + v.z * v.z + v.w * v.w;
#pragma unroll
    for (int off = 32; off > 0; off >>= 1) {
        s  += __shfl_down(s, off);
        ss += __shfl_down(ss, off);
    }
    __shared__ float red[8];
    const int wv = t >> 6;
    if ((t & 63) == 0) { red[wv] = s; red[4 + wv] = ss; }
    __syncthreads();
    if (t == 0) {
        red[0] = red[0] + red[1] + red[2] + red[3];
        red[4] = red[4] + red[5] + red[6] + red[7];
    }
    __syncthreads();
    const float mean = red[0] * (1.0f / 1024.0f);
    const float var  = red[4] * (1.0f / 1024.0f) - mean * mean;
    const float rstd = rsqrtf(var + 1e-5f);
    const float4 gv = ((const float4*)gw)[t];
    const float4 bv = ((const float4*)bw)[t];
    u16x4 o;
    o[0] = f2bf((v.x - mean) * rstd * gv.x + bv.x);
    o[1] = f2bf((v.y - mean) * rstd * gv.y + bv.y);
    o[2] = f2bf((v.z - mean) * rstd * gv.z + bv.z);
    o[3] = f2bf((v.w - mean) * rstd * gv.w + bv.w);
    ((u16x4*)out)[(size_t)row * 256 + t] = o;
}

// ---------------- GEMM: A[M,K] bf16 x Bt[N,K] bf16 -> epilogue ----------------
// EPI 0: QKV split (out0=q [B,H,L,64] scaled 0.125, out1=k [B,H,L,64], out2=vt [B,H,64,L])
// EPI 1: out0 = f32, val + bias + res   (proj + residual)
// EPI 2: out0 = bf16 gelu(val + bias)   (fc1)
// EPI 3: out0 = f32, val + bias + res   (fc2 + residual -> d_out)
template <int BM, int BN, int EPI>
__global__ __launch_bounds__(256, 2) void gemm_bf16(const u16* __restrict__ A,
                                                    const u16* __restrict__ Bt,
                                                    const float* __restrict__ bias,
                                                    const float* __restrict__ res,
                                                    void* __restrict__ out0,
                                                    void* __restrict__ out1,
                                                    void* __restrict__ out2,
                                                    int M, int N, int K) {
    constexpr int WM = BM / 2, WN = BN / 2;
    constexpr int FM = WM / 16, FN = WN / 16;
    __shared__ __align__(16) short Asm[BM * 32];
    __shared__ __align__(16) short Bsm[BN * 32];
    const int tid = threadIdx.x;
    const int lane = tid & 63, wv = tid >> 6;
    const int wr = wv >> 1, wc = wv & 1;
    const int g = lane >> 4, qq = lane & 15;
    const int n0 = blockIdx.x * BN, m0 = blockIdx.y * BM;

    f32x4 acc[FM][FN] = {};

    const char* srcA = (const char*)A + ((size_t)m0 * K) * 2;
    const char* srcB = (const char*)Bt + ((size_t)n0 * K) * 2;
    const size_t strideAB = (size_t)K * 2;

    for (int k0 = 0; k0 < K; k0 += 32) {
        // stage A tile [BM][32] and B tile [BN][32] (both row-major, contiguous)
#pragma unroll
        for (int i = 0; i < BM * 64 / 4096; ++i) {
            const int b = i * 4096 + wv * 1024 + lane * 16;
            const int row = b >> 6, colb = b & 63;
            async_copy16(srcA + (size_t)row * strideAB + (size_t)k0 * 2 + colb,
                         (char*)Asm + i * 4096 + wv * 1024);
        }
#pragma unroll
        for (int i = 0; i < BN * 64 / 4096; ++i) {
            const int b = i * 4096 + wv * 1024 + lane * 16;
            const int row = b >> 6, colb = b & 63;
            async_copy16(srcB + (size_t)row * strideAB + (size_t)k0 * 2 + colb,
                         (char*)Bsm + i * 4096 + wv * 1024);
        }
        __syncthreads();

        bf16x8 af[FM], bfr[FN];
#pragma unroll
        for (int fm = 0; fm < FM; ++fm) {
            const int row = wr * WM + fm * 16 + qq;
            af[fm] = *(const bf16x8*)(&Asm[row * 32 + g * 8]);
        }
#pragma unroll
        for (int fn = 0; fn < FN; ++fn) {
            const int row = wc * WN + fn * 16 + qq;
            bfr[fn] = *(const bf16x8*)(&Bsm[row * 32 + g * 8]);
        }
#pragma unroll
        for (int fm = 0; fm < FM; ++fm) {
#pragma unroll
            for (int fn = 0; fn < FN; ++fn) {
                acc[fm][fn] = __builtin_amdgcn_mfma_f32_16x16x32_bf16(af[fm], bfr[fn],
                                                                      acc[fm][fn], 0, 0, 0);
            }
        }
        __syncthreads();
    }

    // epilogue: lane holds D[(g*4 + r)][qq] per 16x16 fragment
    const int g4 = g * 4;
#pragma unroll
    for (int fm = 0; fm < FM; ++fm) {
#pragma unroll
        for (int fn = 0; fn < FN; ++fn) {
            const int mrow = m0 + wr * WM + fm * 16 + g4;
            const int ncol = n0 + wc * WN + fn * 16 + qq;
            const float bs = bias[ncol];
            if constexpr (EPI == 0) {
                const int sec = ncol >> 10;
                const int hd_ = ncol & 1023;
                const int hh = hd_ >> 6, dd = hd_ & 63;
                if (sec == 2) {
                    const int b_ = mrow >> 11, l_ = mrow & 2047;
                    u16x4 pk;
#pragma unroll
                    for (int r = 0; r < 4; ++r) pk[r] = f2bf(acc[fm][fn][r] + bs);
                    *(u16x4*)((u16*)out2 + ((size_t)((b_ * 16 + hh) * 64 + dd)) * 2048 + l_) = pk;
                } else {
                    u16* dst = (sec == 0) ? (u16*)out0 : (u16*)out1;
                    const float sc = (sec == 0) ? 0.125f : 1.0f;
#pragma unroll
                    for (int r = 0; r < 4; ++r) {
                        const int mr = mrow + r;
                        const int b_ = mr >> 11, l_ = mr & 2047;
                        dst[((size_t)((b_ * 16 + hh) * 2048 + l_)) * 64 + dd] =
                            f2bf((acc[fm][fn][r] + bs) * sc);
                    }
                }
            } else if constexpr (EPI == 1 || EPI == 3) {
                float* dst = (float*)out0;
#pragma unroll
                for (int r = 0; r < 4; ++r) {
                    const int mr = mrow + r;
                    dst[(size_t)mr * N + ncol] = acc[fm][fn][r] + bs + res[(size_t)mr * N + ncol];
                }
            } else {
                u16* dst = (u16*)out0;
#pragma unroll
                for (int r = 0; r < 4; ++r) {
                    float v = acc[fm][fn][r] + bs;
                    v = 0.5f * v * (1.0f + erff(v * 0.70710678118f));
                    dst[(size_t)(mrow + r) * N + ncol] = f2bf(v);
                }
            }
        }
    }
}

// ---------------- causal flash attention (LDS-staged, double-buffered K/V) ----------------
// Q [BH][2048][64] (pre-scaled), K [BH][2048][64], Vt [BH][64][2048] -> Y bf16 [4096][1024]
// One wave owns 16 q rows; swapped QK^T (S^T = K*Q^T) so softmax state is lane-local.
// K/V tiles (64 keys) staged in LDS via global_load_lds with XOR-swizzled SOURCE addresses
// (rule 21: linear LDS dest, pre-swizzled global src, swizzled ds_read).
DEVI void stage_kv(const char* kbase, const char* vbase, int key0,
                   u16* ksm, u16* vsm, int wv, int lane) {
    // K tile: 64 rows x 128B, contiguous 8KB in global (K is [2048][64] bf16)
#pragma unroll
    for (int i = 0; i < 2; ++i) {
        const int c = wv + i * 4;            // 1KB chunk 0..7
        const int off = c * 1024 + lane * 16;
        const int row = off >> 7;            // 0..63
        const int scol = (off & 127) ^ ((row & 7) << 4);
        async_copy16(kbase + (size_t)key0 * 128 + (size_t)row * 128 + scol,
                     (char*)ksm + c * 1024);
    }
    // V^T tile: 64 d-rows x 128B, global row stride 4096B (Vt is [64][2048] bf16)
#pragma unroll
    for (int i = 0; i < 2; ++i) {
        const int c = wv + i * 4;
        const int row = c * 8 + (lane >> 3); // row&7 == lane>>3
        const int scol = ((lane & 7) * 16) ^ ((row & 7) << 4);
        async_copy16(vbase + (size_t)row * 4096 + (size_t)key0 * 2 + scol,
                     (char*)vsm + c * 1024);
    }
}

__global__ __launch_bounds__(256, 3) void attn_kernel(const u16* __restrict__ Q,
                                                      const u16* __restrict__ Kk,
                                                      const u16* __restrict__ Vt,
                                                      u16* __restrict__ Y) {
    const int bh = blockIdx.y;
    const int b_ = bh >> 4, hh = bh & 15;
    const int qb = gridDim.x - 1 - blockIdx.x;   // reversed: longest causal blocks first
    const int tid = threadIdx.x;
    const int wv = tid >> 6, lane = tid & 63;
    const int g = lane >> 4, qi = lane & 15;
    const int xsw = (qi & 7) << 4;               // read-side XOR swizzle (row&7 == qi&7)
    const int q0 = qb * 64 + wv * 16;
    const int qg = q0 + qi;

    __shared__ __align__(16) u16 Ksm[2][4096];   // [buf][64 rows * 64 cols]
    __shared__ __align__(16) u16 Vsm[2][4096];
    __shared__ __align__(16) u16 Pl[4][16][72];  // per-wave P[q][key], padded stride 72

    const u16*  Qb = Q + ((size_t)bh * 2048 + q0) * 64;
    const char* Kb = (const char*)(Kk + (size_t)bh * 2048 * 64);
    const char* Vb = (const char*)(Vt + (size_t)bh * 64 * 2048);

    bf16x8 qf[2];
#pragma unroll
    for (int ks = 0; ks < 2; ++ks)
        qf[ks] = *(const bf16x8*)(Qb + qi * 64 + ks * 32 + g * 8);

    f32x4 oacc[4] = {};
    float m_run = -1e30f, l_run = 0.0f;
    const int ntile = qb + 1;

    stage_kv(Kb, Vb, 0, Ksm[0], Vsm[0], wv, lane);
    __syncthreads();

    int cur = 0;
    for (int kt = 0; kt < ntile; ++kt) {
        const int key0 = kt * 64;
        if (kt + 1 < ntile)
            stage_kv(Kb, Vb, key0 + 64, Ksm[cur ^ 1], Vsm[cur ^ 1], wv, lane);

        // S^T = K * Q^T from LDS (swizzled reads)
        f32x4 sacc[4] = {};
#pragma unroll
        for (int ks = 0; ks < 2; ++ks) {
#pragma unroll
            for (int kc = 0; kc < 4; ++kc) {
                const int rk = kc * 16 + qi;
                const bf16x8 ak = *(const bf16x8*)((const char*)Ksm[cur] + rk * 128 +
                                                   ((ks * 64 + g * 16) ^ xsw));
                sacc[kc] = __builtin_amdgcn_mfma_f32_16x16x32_bf16(ak, qf[ks], sacc[kc], 0, 0, 0);
            }
        }

        // lane holds S[q=qi][key = key0 + kc*16 + g*4 + r]
        float p[4][4];
        float mymax = -1e30f;
        if (kt == ntile - 1) {   // only the diagonal tile needs the causal mask (uniform branch)
#pragma unroll
            for (int kc = 0; kc < 4; ++kc) {
#pragma unroll
                for (int r = 0; r < 4; ++r) {
                    const int key = key0 + kc * 16 + g * 4 + r;
                    float sv = sacc[kc][r];
                    if (key > qg) sv = -__builtin_inff();
                    p[kc][r] = sv;
                    mymax = fmaxf(mymax, sv);
                }
            }
        } else {
#pragma unroll
            for (int kc = 0; kc < 4; ++kc) {
#pragma unroll
                for (int r = 0; r < 4; ++r) {
                    p[kc][r] = sacc[kc][r];
                    mymax = fmaxf(mymax, sacc[kc][r]);
                }
            }
        }
        mymax = fmaxf(mymax, __shfl_xor(mymax, 16));
        mymax = fmaxf(mymax, __shfl_xor(mymax, 32));
        const float m_new = fmaxf(m_run, mymax);
        const float alpha = __expf(m_run - m_new);
        float lsum = 0.0f;
#pragma unroll
        for (int kc = 0; kc < 4; ++kc) {
#pragma unroll
            for (int r = 0; r < 4; ++r) {
                const float e = __expf(p[kc][r] - m_new);
                p[kc][r] = e;
                lsum += e;
            }
        }
        lsum += __shfl_xor(lsum, 16);
        lsum += __shfl_xor(lsum, 32);
        l_run = l_run * alpha + lsum;
        m_run = m_new;
#pragma unroll
        for (int c = 0; c < 4; ++c) {
#pragma unroll
            for (int r = 0; r < 4; ++r) oacc[c][r] *= alpha;
        }
        // P -> LDS [q][key] (bf16), then reload as PV B-operand fragments
#pragma unroll
        for (int kc = 0; kc < 4; ++kc) {
            u16x4 pk;
#pragma unroll
            for (int r = 0; r < 4; ++r) pk[r] = f2bf(p[kc][r]);
            *(u16x4*)(&Pl[wv][qi][kc * 16 + g * 4]) = pk;
        }
        bf16x8 pb[2];
#pragma unroll
        for (int ks = 0; ks < 2; ++ks)
            pb[ks] = *(const bf16x8*)(&Pl[wv][qi][ks * 32 + g * 8]);
        // O^T += V^T * P^T : A = Vt rows (d) from LDS, B = P
#pragma unroll
        for (int ks = 0; ks < 2; ++ks) {
#pragma unroll
            for (int c = 0; c < 4; ++c) {
                const int rv = c * 16 + qi;
                const bf16x8 av = *(const bf16x8*)((const char*)Vsm[cur] + rv * 128 +
                                                   ((ks * 64 + g * 16) ^ xsw));
                oacc[c] = __builtin_amdgcn_mfma_f32_16x16x32_bf16(av, pb[ks], oacc[c], 0, 0, 0);
            }
        }

        __syncthreads();   // drains prefetch vmcnt + protects buffer reuse
        cur ^= 1;
    }

    const float inv = 1.0f / l_run;
#pragma unroll
    for (int c = 0; c < 4; ++c) {
        u16x4 o;
#pragma unroll
        for (int r = 0; r < 4; ++r) o[r] = f2bf(oacc[c][r] * inv);
        *(u16x4*)(&Y[((size_t)(b_ * 2048 + qg)) * 1024 + hh * 64 + c * 16 + g * 4]) = o;
    }
}

// ---------------- host ----------------
extern "C" void kernel_launch(void* const* d_in, const int* in_sizes, int n_in,
                              void* d_out, int out_size, void* d_ws, size_t ws_size,
                              hipStream_t stream) {
    (void)in_sizes; (void)n_in; (void)out_size;
    const float* x      = (const float*)d_in[0];
    const float* w_qkv  = (const float*)d_in[2];
    const float* b_qkv  = (const float*)d_in[3];
    const float* w_proj = (const float*)d_in[4];
    const float* b_proj = (const float*)d_in[5];
    const float* w_fc1  = (const float*)d_in[6];
    const float* b_fc1  = (const float*)d_in[7];
    const float* w_fc2  = (const float*)d_in[8];
    const float* b_fc2  = (const float*)d_in[9];
    const float* g1     = (const float*)d_in[10];
    const float* be1    = (const float*)d_in[11];
    const float* g2     = (const float*)d_in[12];
    const float* be2    = (const float*)d_in[13];

    char* ws = (char*)d_ws;
    size_t off = 0;
    auto alloc = [&](size_t bytes) { size_t r = off; off += (bytes + 255) & ~(size_t)255; return r; };
    u16*   wt_qkv = (u16*)(ws + alloc((size_t)3072 * 1024 * 2));
    u16*   wt_prj = (u16*)(ws + alloc((size_t)1024 * 1024 * 2));
    u16*   wt_fc1 = (u16*)(ws + alloc((size_t)4096 * 1024 * 2));
    u16*   wt_fc2 = (u16*)(ws + alloc((size_t)1024 * 4096 * 2));
    u16*   hbuf   = (u16*)(ws + alloc((size_t)4096 * 1024 * 2));   // ln out (reused for ln2)
    float* x1     = (float*)(ws + alloc((size_t)4096 * 1024 * 4)); // residual after attn
    char*  big    = ws + alloc((size_t)33554432);                  // q,k,vt,y  OR  act
    u16* qb  = (u16*)(big);
    u16* kb  = (u16*)(big + 8388608);
    u16* vtb = (u16*)(big + 16777216);
    u16* yb  = (u16*)(big + 25165824);
    u16* act = (u16*)(big);                                        // reuse after attention is done
    if (off > ws_size) return;  // workspace too small: bail (harness will flag mismatch)

    const dim3 blk(256);
    // weights -> bf16 transposed [N][K]
    tcvt_kernel<<<dim3(32, 96), blk, 0, stream>>>(w_qkv, wt_qkv, 1024, 3072);
    tcvt_kernel<<<dim3(32, 32), blk, 0, stream>>>(w_proj, wt_prj, 1024, 1024);
    tcvt_kernel<<<dim3(32, 128), blk, 0, stream>>>(w_fc1, wt_fc1, 1024, 4096);
    tcvt_kernel<<<dim3(128, 32), blk, 0, stream>>>(w_fc2, wt_fc2, 4096, 1024);

    // LN1
    ln_kernel<<<dim3(4096), blk, 0, stream>>>(x, g1, be1, hbuf);
    // QKV gemm + head-split epilogue
    gemm_bf16<128, 128, 0><<<dim3(24, 32), blk, 0, stream>>>(hbuf, wt_qkv, b_qkv, nullptr,
                                                             qb, kb, vtb, 4096, 3072, 1024);
    // attention
    attn_kernel<<<dim3(32, 32), blk, 0, stream>>>(qb, kb, vtb, yb);
    // proj + residual (f32)
    gemm_bf16<64, 128, 1><<<dim3(8, 64), blk, 0, stream>>>(yb, wt_prj, b_proj, x,
                                                           x1, nullptr, nullptr, 4096, 1024, 1024);
    // LN2
    ln_kernel<<<dim3(4096), blk, 0, stream>>>(x1, g2, be2, hbuf);
    // FC1 + GELU
    gemm_bf16<128, 128, 2><<<dim3(32, 32), blk, 0, stream>>>(hbuf, wt_fc1, b_fc1, nullptr,
                                                             act, nullptr, nullptr, 4096, 4096, 1024);
    // FC2 + residual -> out (f32)
    gemm_bf16<64, 128, 3><<<dim3(8, 64), blk, 0, stream>>>(act, wt_fc2, b_fc2, x1,
                                                           (float*)d_out, nullptr, nullptr,
                                                           4096, 1024, 4096);
}